// Round 4
// baseline (373.198 us; speedup 1.0000x reference)
//
#include <hip/hip_runtime.h>

// GCN 2-layer forward, f32 — CSR-gather; coalesced edge-record load + register
// shfl distribution so row gathers issue with deep memory-level parallelism.
// Algebra: A_hat(X@W1) = (A_hat X)@W1; layer 2 is scalar aggregation of s=h@W2.

#define NNODES 100000
#define INF 64
#define HID 128

typedef unsigned long long u64;

__global__ void k_hist(const int* __restrict__ dst, int* __restrict__ cnt, int nE) {
    int e = blockIdx.x * blockDim.x + threadIdx.x;
    if (e < nE) {
        int d = dst[e];
        if ((unsigned)d < (unsigned)NNODES) atomicAdd(&cnt[d], 1);
    }
}

// block-level exclusive scan: 256 thr x 4 elems = 1024/block
__global__ void k_scan1(const int* __restrict__ cnt, int* __restrict__ excl,
                        int* __restrict__ bsums, int n) {
    __shared__ int tmp[256];
    int tid = threadIdx.x;
    int base = blockIdx.x * 1024 + tid * 4;
    int v0 = (base + 0 < n) ? cnt[base + 0] : 0;
    int v1 = (base + 1 < n) ? cnt[base + 1] : 0;
    int v2 = (base + 2 < n) ? cnt[base + 2] : 0;
    int v3 = (base + 3 < n) ? cnt[base + 3] : 0;
    int t = v0 + v1 + v2 + v3;
    tmp[tid] = t;
    __syncthreads();
    for (int off = 1; off < 256; off <<= 1) {
        int u = (tid >= off) ? tmp[tid - off] : 0;
        __syncthreads();
        tmp[tid] += u;
        __syncthreads();
    }
    int ex = tmp[tid] - t;
    if (base + 0 < n) excl[base + 0] = ex;
    if (base + 1 < n) excl[base + 1] = ex + v0;
    if (base + 2 < n) excl[base + 2] = ex + v0 + v1;
    if (base + 3 < n) excl[base + 3] = ex + v0 + v1 + v2;
    if (tid == 255) bsums[blockIdx.x] = tmp[255];
}

__global__ void k_scan2(int* bsums, int nb) {
    __shared__ int tmp[256];
    int tid = threadIdx.x;
    int t = (tid < nb) ? bsums[tid] : 0;
    tmp[tid] = t;
    __syncthreads();
    for (int off = 1; off < 256; off <<= 1) {
        int u = (tid >= off) ? tmp[tid - off] : 0;
        __syncthreads();
        tmp[tid] += u;
        __syncthreads();
    }
    if (tid < nb) bsums[tid] = tmp[tid] - t;
}

// finalize rowPtr/cursor + compute dinv (folded)
__global__ void k_finalize(int* __restrict__ rowPtr, int* __restrict__ cursor,
                           const int* __restrict__ bsums, const int* __restrict__ counts,
                           float* __restrict__ dinv, int n, int E) {
    int i = blockIdx.x * blockDim.x + threadIdx.x;
    if (i < n) {
        int v = rowPtr[i] + bsums[i >> 10];
        rowPtr[i] = v;
        cursor[i] = v;
        dinv[i] = rsqrtf((float)(counts[i] + 1));  // +1 self loop
    }
    if (i == 0) rowPtr[n] = E;
}

// fill CSR with packed (src, w=dinv[src]) 8B records
__global__ void k_fill(const int* __restrict__ srcA, const int* __restrict__ dstA,
                       const float* __restrict__ dinv, int* __restrict__ cursor,
                       u64* __restrict__ eSW, int nE) {
    int e = blockIdx.x * blockDim.x + threadIdx.x;
    if (e < nE) {
        int s = srcA[e];
        int d = dstA[e];
        if ((unsigned)s < (unsigned)NNODES && (unsigned)d < (unsigned)NNODES) {
            int pos = atomicAdd(&cursor[d], 1);
            eSW[pos] = (u64)(unsigned)s | ((u64)__float_as_uint(dinv[s]) << 32);
        }
    }
}

// wave per node. One coalesced 8B/lane load grabs 64 edge records; src/w are
// distributed from registers via shfl so quarter-wave float4 row gathers issue
// back-to-back (deep MLP). Quarter q handles edges idx = q + 4k (interleaved).
// Then in-register MLP: sv[node] = dot(relu(agg@W1 + b1), W2)
__global__ __launch_bounds__(1024) void k_agg_mlp(const float4* __restrict__ X4,
                                                  const int* __restrict__ rowPtr,
                                                  const u64* __restrict__ eSW,
                                                  const float* __restrict__ dinv,
                                                  const float* __restrict__ W1,
                                                  const float* __restrict__ b1,
                                                  const float* __restrict__ W2,
                                                  float* __restrict__ sv, int n) {
    __shared__ float W1s[INF * HID];  // 32 KB
    __shared__ float b1s[HID];
    __shared__ float W2s[HID];
    for (int i = threadIdx.x; i < INF * HID / 4; i += blockDim.x)
        ((float4*)W1s)[i] = ((const float4*)W1)[i];
    if (threadIdx.x < HID) {
        b1s[threadIdx.x] = b1[threadIdx.x];
        W2s[threadIdx.x] = W2[threadIdx.x];
    }
    __syncthreads();

    int lane = threadIdx.x & 63;
    int r = lane & 15;        // float4 slot within row
    int q = lane >> 4;        // quarter id
    int node = (blockIdx.x * blockDim.x + threadIdx.x) >> 6;
    if (node >= n) return;

    int beg = rowPtr[node];
    int end = rowPtr[node + 1];
    float dD = dinv[node];

    // self-loop term (only quarter 0 contributes)
    float4 acc = {0.0f, 0.0f, 0.0f, 0.0f};
    if (q == 0) {
        float4 xn = X4[(size_t)node * 16 + r];
        acc.x = dD * xn.x; acc.y = dD * xn.y; acc.z = dD * xn.z; acc.w = dD * xn.w;
    }

    for (int j0 = beg; j0 < end; j0 += 64) {
        int m = end - j0;  // may exceed 64; handled by next iteration
        int si = 0;
        float wi = 0.0f;
        if (lane < m) {
            u64 p = eSW[j0 + lane];  // coalesced 8B/lane
            si = (int)(unsigned)p;
            wi = __uint_as_float((unsigned)(p >> 32));
        }
#pragma unroll
        for (int k = 0; k < 16; ++k) {
            int idx = q + 4 * k;  // interleaved: deg=16 -> 4 edges per quarter
            int s = __shfl(si, idx, 64);
            float w = __shfl(wi, idx, 64);
            if (idx < m) {
                float4 x = X4[(size_t)s * 16 + r];
                acc.x = fmaf(w, x.x, acc.x); acc.y = fmaf(w, x.y, acc.y);
                acc.z = fmaf(w, x.z, acc.z); acc.w = fmaf(w, x.w, acc.w);
            }
        }
    }

    // reduce the 4 quarters; afterwards every lane with same r holds full sum
    acc.x += __shfl_xor(acc.x, 16, 64); acc.y += __shfl_xor(acc.y, 16, 64);
    acc.z += __shfl_xor(acc.z, 16, 64); acc.w += __shfl_xor(acc.w, 16, 64);
    acc.x += __shfl_xor(acc.x, 32, 64); acc.y += __shfl_xor(acc.y, 32, 64);
    acc.z += __shfl_xor(acc.z, 32, 64); acc.w += __shfl_xor(acc.w, 32, 64);

    // agg[4r+c] = dD * acc.c   (lane r, any quarter)
    float av0 = dD * acc.x, av1 = dD * acc.y, av2 = dD * acc.z, av3 = dD * acc.w;

    float a0 = 0.0f, a1 = 0.0f;
#pragma unroll
    for (int k = 0; k < INF; ++k) {
        float srcv = ((k & 3) == 0) ? av0 : ((k & 3) == 1) ? av1 : ((k & 3) == 2) ? av2 : av3;
        float xk = __shfl(srcv, k >> 2, 64);  // feature k lives in lane k>>2, comp k&3
        a0 = fmaf(xk, W1s[k * HID + lane], a0);
        a1 = fmaf(xk, W1s[k * HID + 64 + lane], a1);
    }
    float h0 = fmaxf(a0 + b1s[lane], 0.0f);
    float h1 = fmaxf(a1 + b1s[64 + lane], 0.0f);
    float p = h0 * W2s[lane] + h1 * W2s[64 + lane];
#pragma unroll
    for (int off = 32; off > 0; off >>= 1) p += __shfl_xor(p, off, 64);
    if (lane == 0) sv[node] = p;
}

// 4 nodes per wave (16-lane segments): out = dD*sum(w*sv[src]) + dD^2*sv[node] + b2
__global__ __launch_bounds__(256) void k_out(const int* __restrict__ rowPtr,
                                             const u64* __restrict__ eSW,
                                             const float* __restrict__ dinv,
                                             const float* __restrict__ sv,
                                             const float* __restrict__ b2,
                                             float* __restrict__ out, int n) {
    int t = blockIdx.x * blockDim.x + threadIdx.x;
    int node = t >> 4;
    int r = t & 15;
    if (node >= n) return;
    int beg = rowPtr[node];
    int end = rowPtr[node + 1];
    float p = 0.0f;
    for (int j = beg + r; j < end; j += 16) {
        u64 pe = eSW[j];
        int s = (int)(unsigned)pe;
        float w = __uint_as_float((unsigned)(pe >> 32));
        p = fmaf(w, sv[s], p);
    }
    p += __shfl_xor(p, 1, 16);
    p += __shfl_xor(p, 2, 16);
    p += __shfl_xor(p, 4, 16);
    p += __shfl_xor(p, 8, 16);
    if (r == 0) {
        float dD = dinv[node];
        out[node] = fmaf(dD, p, fmaf(dD * dD, sv[node], b2[0]));
    }
}

extern "C" void kernel_launch(void* const* d_in, const int* in_sizes, int n_in,
                              void* d_out, int out_size, void* d_ws, size_t ws_size,
                              hipStream_t stream) {
    const float* X  = (const float*)d_in[0];
    const int*   ei = (const int*)d_in[1];   // int32 (jax x64 disabled)
    const float* W1 = (const float*)d_in[2];
    const float* b1 = (const float*)d_in[3];
    const float* W2 = (const float*)d_in[4];
    const float* b2 = (const float*)d_in[5];

    int N = in_sizes[0] / INF;  // 100000
    int E = in_sizes[1] / 2;    // 1600000

    const int* srcA = ei;
    const int* dstA = ei + E;

    // workspace layout (eSW first for 8B alignment)
    u64*   eSW    = (u64*)d_ws;             // E
    int*   counts = (int*)(eSW + E);        // N
    int*   rowPtr = counts + N;             // N+1
    int*   cursor = rowPtr + N + 1;         // N
    int*   bsums  = cursor + N;             // 256
    float* dinv   = (float*)(bsums + 256);  // N
    float* sv     = dinv + N;               // N
    float* out    = (float*)d_out;

    int nbN = (N + 255) / 256;
    int nbE = (E + 255) / 256;
    int nb1 = (N + 1023) / 1024;  // 98 blocks for scan1

    hipMemsetAsync(counts, 0, (size_t)N * sizeof(int), stream);
    k_hist<<<nbE, 256, 0, stream>>>(dstA, counts, E);
    k_scan1<<<nb1, 256, 0, stream>>>(counts, rowPtr, bsums, N);
    k_scan2<<<1, 256, 0, stream>>>(bsums, nb1);
    k_finalize<<<nbN, 256, 0, stream>>>(rowPtr, cursor, bsums, counts, dinv, N, E);
    k_fill<<<nbE, 256, 0, stream>>>(srcA, dstA, dinv, cursor, eSW, E);
    k_agg_mlp<<<(N * 64 + 1023) / 1024, 1024, 0, stream>>>((const float4*)X, rowPtr, eSW,
                                                           dinv, W1, b1, W2, sv, N);
    k_out<<<(N * 16 + 255) / 256, 256, 0, stream>>>(rowPtr, eSW, dinv, sv, b2, out, N);
}

// Round 5
// 341.080 us; speedup vs baseline: 1.0942x; 1.0942x over previous
//
#include <hip/hip_runtime.h>

// GCN 2-layer forward, f32 — CSR-gather. Edge records staged via LDS so the
// row-gather address chain never waits on a cold-HBM record load.
// Algebra: A_hat(X@W1) = (A_hat X)@W1; layer 2 is scalar aggregation of s=h@W2.

#define NNODES 100000
#define INF 64
#define HID 128
#define NPB 16       // nodes per block (16 waves x 1 node)
#define REC_CAP 1536 // LDS record capacity (mean usage ~256; overflow -> global)

typedef unsigned long long u64;

__global__ void k_hist(const int* __restrict__ dst, int* __restrict__ cnt, int nE) {
    int e = blockIdx.x * blockDim.x + threadIdx.x;
    if (e < nE) {
        int d = dst[e];
        if ((unsigned)d < (unsigned)NNODES) atomicAdd(&cnt[d], 1);
    }
}

// block-level exclusive scan: 256 thr x 4 elems = 1024/block
__global__ void k_scan1(const int* __restrict__ cnt, int* __restrict__ excl,
                        int* __restrict__ bsums, int n) {
    __shared__ int tmp[256];
    int tid = threadIdx.x;
    int base = blockIdx.x * 1024 + tid * 4;
    int v0 = (base + 0 < n) ? cnt[base + 0] : 0;
    int v1 = (base + 1 < n) ? cnt[base + 1] : 0;
    int v2 = (base + 2 < n) ? cnt[base + 2] : 0;
    int v3 = (base + 3 < n) ? cnt[base + 3] : 0;
    int t = v0 + v1 + v2 + v3;
    tmp[tid] = t;
    __syncthreads();
    for (int off = 1; off < 256; off <<= 1) {
        int u = (tid >= off) ? tmp[tid - off] : 0;
        __syncthreads();
        tmp[tid] += u;
        __syncthreads();
    }
    int ex = tmp[tid] - t;
    if (base + 0 < n) excl[base + 0] = ex;
    if (base + 1 < n) excl[base + 1] = ex + v0;
    if (base + 2 < n) excl[base + 2] = ex + v0 + v1;
    if (base + 3 < n) excl[base + 3] = ex + v0 + v1 + v2;
    if (tid == 255) bsums[blockIdx.x] = tmp[255];
}

__global__ void k_scan2(int* bsums, int nb) {
    __shared__ int tmp[256];
    int tid = threadIdx.x;
    int t = (tid < nb) ? bsums[tid] : 0;
    tmp[tid] = t;
    __syncthreads();
    for (int off = 1; off < 256; off <<= 1) {
        int u = (tid >= off) ? tmp[tid - off] : 0;
        __syncthreads();
        tmp[tid] += u;
        __syncthreads();
    }
    if (tid < nb) bsums[tid] = tmp[tid] - t;
}

// finalize rowPtr/cursor + compute dinv (folded)
__global__ void k_finalize(int* __restrict__ rowPtr, int* __restrict__ cursor,
                           const int* __restrict__ bsums, const int* __restrict__ counts,
                           float* __restrict__ dinv, int n, int E) {
    int i = blockIdx.x * blockDim.x + threadIdx.x;
    if (i < n) {
        int v = rowPtr[i] + bsums[i >> 10];
        rowPtr[i] = v;
        cursor[i] = v;
        dinv[i] = rsqrtf((float)(counts[i] + 1));  // +1 self loop
    }
    if (i == 0) rowPtr[n] = E;
}

// fill CSR with packed (src, w=dinv[src]) 8B records
__global__ void k_fill(const int* __restrict__ srcA, const int* __restrict__ dstA,
                       const float* __restrict__ dinv, int* __restrict__ cursor,
                       u64* __restrict__ eSW, int nE) {
    int e = blockIdx.x * blockDim.x + threadIdx.x;
    if (e < nE) {
        int s = srcA[e];
        int d = dstA[e];
        if ((unsigned)s < (unsigned)NNODES && (unsigned)d < (unsigned)NNODES) {
            int pos = atomicAdd(&cursor[d], 1);
            eSW[pos] = (u64)(unsigned)s | ((u64)__float_as_uint(dinv[s]) << 32);
        }
    }
}

// 16 waves/block, wave per node, quarter-wave (16 lanes x float4) per edge.
// Block cooperatively stages this block's contiguous eSW range into LDS first;
// per-quarter loop then chains LDS-read -> row gather (no HBM chain head).
// Then in-register MLP: sv[node] = dot(relu(agg@W1 + b1), W2)
__global__ __launch_bounds__(1024) void k_agg_mlp(const float4* __restrict__ X4,
                                                  const int* __restrict__ rowPtr,
                                                  const u64* __restrict__ eSW,
                                                  const float* __restrict__ dinv,
                                                  const float* __restrict__ W1,
                                                  const float* __restrict__ b1,
                                                  const float* __restrict__ W2,
                                                  float* __restrict__ sv, int n) {
    __shared__ float W1s[INF * HID];  // 32 KB
    __shared__ float b1s[HID];
    __shared__ float W2s[HID];
    __shared__ u64 recs[REC_CAP];     // 12 KB
    for (int i = threadIdx.x; i < INF * HID / 4; i += blockDim.x)
        ((float4*)W1s)[i] = ((const float4*)W1)[i];
    if (threadIdx.x < HID) {
        b1s[threadIdx.x] = b1[threadIdx.x];
        W2s[threadIdx.x] = W2[threadIdx.x];
    }

    int n0 = blockIdx.x * NPB;
    int nEndNode = min(n0 + NPB, n);
    int rBeg = rowPtr[n0];
    int rEnd = rowPtr[nEndNode];
    int total = min(rEnd - rBeg, REC_CAP);
    for (int i = threadIdx.x; i < total; i += blockDim.x)
        recs[i] = eSW[rBeg + i];  // coalesced 8B/lane
    __syncthreads();

    int lane = threadIdx.x & 63;
    int r = lane & 15;   // float4 slot within row
    int q = lane >> 4;   // quarter id
    int node = n0 + (threadIdx.x >> 6);
    if (node >= n) return;

    int beg = rowPtr[node];
    int end = rowPtr[node + 1];
    float dD = dinv[node];

    // self-loop term (only quarter 0 contributes)
    float4 acc = {0.0f, 0.0f, 0.0f, 0.0f};
    if (q == 0) {
        float4 xn = X4[(size_t)node * 16 + r];
        acc.x = dD * xn.x; acc.y = dD * xn.y; acc.z = dD * xn.z; acc.w = dD * xn.w;
    }

    int lbeg = beg - rBeg + q;
    int lend = end - rBeg;
#pragma unroll 2
    for (int jj = lbeg; jj < lend; jj += 4) {
        u64 p = (jj < REC_CAP) ? recs[jj] : eSW[rBeg + jj];
        int s = (int)(unsigned)p;
        float w = __uint_as_float((unsigned)(p >> 32));
        float4 x = X4[(size_t)s * 16 + r];
        acc.x = fmaf(w, x.x, acc.x); acc.y = fmaf(w, x.y, acc.y);
        acc.z = fmaf(w, x.z, acc.z); acc.w = fmaf(w, x.w, acc.w);
    }

    // reduce the 4 quarters; afterwards every lane with same r holds full sum
    acc.x += __shfl_xor(acc.x, 16, 64); acc.y += __shfl_xor(acc.y, 16, 64);
    acc.z += __shfl_xor(acc.z, 16, 64); acc.w += __shfl_xor(acc.w, 16, 64);
    acc.x += __shfl_xor(acc.x, 32, 64); acc.y += __shfl_xor(acc.y, 32, 64);
    acc.z += __shfl_xor(acc.z, 32, 64); acc.w += __shfl_xor(acc.w, 32, 64);

    // agg[4r+c] = dD * acc.c   (lane r, any quarter)
    float av0 = dD * acc.x, av1 = dD * acc.y, av2 = dD * acc.z, av3 = dD * acc.w;

    float a0 = 0.0f, a1 = 0.0f;
#pragma unroll
    for (int k = 0; k < INF; ++k) {
        float srcv = ((k & 3) == 0) ? av0 : ((k & 3) == 1) ? av1 : ((k & 3) == 2) ? av2 : av3;
        float xk = __shfl(srcv, k >> 2, 64);  // feature k lives in lane k>>2, comp k&3
        a0 = fmaf(xk, W1s[k * HID + lane], a0);
        a1 = fmaf(xk, W1s[k * HID + 64 + lane], a1);
    }
    float h0 = fmaxf(a0 + b1s[lane], 0.0f);
    float h1 = fmaxf(a1 + b1s[64 + lane], 0.0f);
    float p = h0 * W2s[lane] + h1 * W2s[64 + lane];
#pragma unroll
    for (int off = 32; off > 0; off >>= 1) p += __shfl_xor(p, off, 64);
    if (lane == 0) sv[node] = p;
}

// 4 nodes per wave (16-lane segments): out = dD*sum(w*sv[src]) + dD^2*sv[node] + b2
__global__ __launch_bounds__(256) void k_out(const int* __restrict__ rowPtr,
                                             const u64* __restrict__ eSW,
                                             const float* __restrict__ dinv,
                                             const float* __restrict__ sv,
                                             const float* __restrict__ b2,
                                             float* __restrict__ out, int n) {
    int t = blockIdx.x * blockDim.x + threadIdx.x;
    int node = t >> 4;
    int r = t & 15;
    if (node >= n) return;
    int beg = rowPtr[node];
    int end = rowPtr[node + 1];
    float p = 0.0f;
    for (int j = beg + r; j < end; j += 16) {
        u64 pe = eSW[j];
        int s = (int)(unsigned)pe;
        float w = __uint_as_float((unsigned)(pe >> 32));
        p = fmaf(w, sv[s], p);
    }
    p += __shfl_xor(p, 1, 16);
    p += __shfl_xor(p, 2, 16);
    p += __shfl_xor(p, 4, 16);
    p += __shfl_xor(p, 8, 16);
    if (r == 0) {
        float dD = dinv[node];
        out[node] = fmaf(dD, p, fmaf(dD * dD, sv[node], b2[0]));
    }
}

extern "C" void kernel_launch(void* const* d_in, const int* in_sizes, int n_in,
                              void* d_out, int out_size, void* d_ws, size_t ws_size,
                              hipStream_t stream) {
    const float* X  = (const float*)d_in[0];
    const int*   ei = (const int*)d_in[1];   // int32 (jax x64 disabled)
    const float* W1 = (const float*)d_in[2];
    const float* b1 = (const float*)d_in[3];
    const float* W2 = (const float*)d_in[4];
    const float* b2 = (const float*)d_in[5];

    int N = in_sizes[0] / INF;  // 100000
    int E = in_sizes[1] / 2;    // 1600000

    const int* srcA = ei;
    const int* dstA = ei + E;

    // workspace layout (eSW first for 8B alignment)
    u64*   eSW    = (u64*)d_ws;             // E
    int*   counts = (int*)(eSW + E);        // N
    int*   rowPtr = counts + N;             // N+1
    int*   cursor = rowPtr + N + 1;         // N
    int*   bsums  = cursor + N;             // 256
    float* dinv   = (float*)(bsums + 256);  // N
    float* sv     = dinv + N;               // N
    float* out    = (float*)d_out;

    int nbN = (N + 255) / 256;
    int nbE = (E + 255) / 256;
    int nb1 = (N + 1023) / 1024;  // 98 blocks for scan1

    hipMemsetAsync(counts, 0, (size_t)N * sizeof(int), stream);
    k_hist<<<nbE, 256, 0, stream>>>(dstA, counts, E);
    k_scan1<<<nb1, 256, 0, stream>>>(counts, rowPtr, bsums, N);
    k_scan2<<<1, 256, 0, stream>>>(bsums, nb1);
    k_finalize<<<nbN, 256, 0, stream>>>(rowPtr, cursor, bsums, counts, dinv, N, E);
    k_fill<<<nbE, 256, 0, stream>>>(srcA, dstA, dinv, cursor, eSW, E);
    k_agg_mlp<<<(N + NPB - 1) / NPB, 1024, 0, stream>>>((const float4*)X, rowPtr, eSW,
                                                        dinv, W1, b1, W2, sv, N);
    k_out<<<(N * 16 + 255) / 256, 256, 0, stream>>>(rowPtr, eSW, dinv, sv, b2, out, N);
}